// Round 5
// baseline (1034.592 us; speedup 1.0000x reference)
//
#include <hip/hip_runtime.h>
#include <hip/hip_fp16.h>

#define DEV static __device__ __forceinline__

typedef _Float16 f16;
typedef _Float16 f16x8 __attribute__((ext_vector_type(8)));
typedef _Float16 f16x4 __attribute__((ext_vector_type(4)));
typedef float f32x4 __attribute__((ext_vector_type(4)));
typedef float f32x16 __attribute__((ext_vector_type(16)));

constexpr int BATCH = 16384;
constexpr int D = 1024;
constexpr int HR = 4096;
constexpr int NOUT = 10;

// ---------------------------------------------------------------- converts
__global__ void k_f32_to_f16(const float* __restrict__ src, f16* __restrict__ dst, int n4) {
    int i = blockIdx.x * blockDim.x + threadIdx.x;
    int stride = gridDim.x * blockDim.x;
    for (; i < n4; i += stride) {
        float4 v = reinterpret_cast<const float4*>(src)[i];
        f16x4 h;
        h[0] = (f16)v.x; h[1] = (f16)v.y; h[2] = (f16)v.z; h[3] = (f16)v.w;
        reinterpret_cast<f16x4*>(dst)[i] = h;
    }
}

// ---------------------------------------------------------------- helpers
DEV void stage16(void* lds, const void* g) {
    __builtin_amdgcn_global_load_lds(
        (const __attribute__((address_space(1))) void*)g,
        (__attribute__((address_space(3))) void*)lds,
        16, 0, 0);
}

// Fragment-major staging source.  LDS region = array of 1KB fragment blocks
// (f = msub*2 + kstep); within a block, unit l = half*32 + row5 holds the
// 16B the lane l of a wave needs for mfma_32x32x16 (row = msub*32+row5,
// k-bytes = kstep*32 + half*16).  Unit u (=tid) lands at LDS offset u*16.
DEV const char* src_ptr(const void* base, int u, int row0, int rowBytes) {
    const int msub = u >> 7;
    const int kstep = (u >> 6) & 1;
    const int half = (u >> 5) & 1;
    const int row5 = u & 31;
    return (const char*)base + (size_t)(row0 + msub * 32 + row5) * rowBytes
           + kstep * 32 + half * 16;
}

DEV int xcd_swz(int bid, int nwg) {        // nwg % 8 == 0 in all our grids
    const int cpx = nwg >> 3;
    return (bid & 7) * cpx + (bid >> 3);
}

// ---------------------------------------------------------------- GEMM1: dual projection + bilinear fuse
// Xh:[M,1024], Wr/Wl:[4096,1024] (NxK); inter[b,n] = (X.Wr[n]+br)*(X.Wl[n]+bl)
// Block 256(M) x 128(N), BK=32; 8 waves (2M x 4N); wave tile 128x32 for both
// R and L (A reused).  MFMA 32x32x16.  LDS ring: 3 x (A 16KB + Br 8KB + Bl 8KB).
__global__ __launch_bounds__(512, 2) void k_gemm_dual(
    const f16* __restrict__ Xh, const f16* __restrict__ Wr, const f16* __restrict__ Wl,
    const float* __restrict__ br, const float* __restrict__ bl,
    f16* __restrict__ inter, int MT)
{
    extern __shared__ __align__(16) char smem[];
    constexpr int K = 1024, NT = K / 32;
    constexpr int BUF = 32 * 1024;

    const int swz = xcd_swz(blockIdx.x, gridDim.x);
    const int mt = swz % MT, nt = swz / MT;
    const int m0 = mt * 256, n0 = nt * 128;
    const int tid = threadIdx.x;
    const int wid = tid >> 6, lane = tid & 63;
    const int wm = wid >> 2, wn = wid & 3;

    const char* sA0 = src_ptr(Xh, tid, m0,       2048);
    const char* sA1 = src_ptr(Xh, tid, m0 + 128, 2048);
    const char* sR  = src_ptr(Wr, tid, n0,       2048);
    const char* sL  = src_ptr(Wl, tid, n0,       2048);
    const int dA0 = tid * 16, dA1 = 8192 + tid * 16;
    const int dR = 16384 + tid * 16, dL = 24576 + tid * 16;

    const int aoff = wm * 8192 + lane * 16;            // + m*2048 + ks*1024
    const int boff = wn * 2048 + lane * 16;            // + ks*1024

    f32x16 accR[4] = {};
    f32x16 accL[4] = {};

    for (int t = 0; t < 2; ++t) {
        char* b = smem + t * BUF;
        const long ko = (long)t * 64;
        stage16(b + dA0, sA0 + ko);  stage16(b + dA1, sA1 + ko);
        stage16(b + dR,  sR  + ko);  stage16(b + dL,  sL  + ko);
    }
    asm volatile("s_waitcnt vmcnt(4)" ::: "memory");
    __builtin_amdgcn_s_barrier();

    int cur = 0;
    long koff = 128;
    for (int t = 0; t < NT; ++t) {
        char* base = smem + cur * BUF;
        const int stg = cur ? cur - 1 : 2;
        char* nb = smem + stg * BUF;
        const bool pf = (t + 2) < NT;

        f16x8 a[4], bR, bL;
        // ---------------- phase 0: kstep 0
#pragma unroll
        for (int m = 0; m < 4; ++m)
            a[m] = *(const f16x8*)(base + aoff + m * 2048);
        bR = *(const f16x8*)(base + 16384 + boff);
        bL = *(const f16x8*)(base + 24576 + boff);
        if (pf) { stage16(nb + dA0, sA0 + koff);  stage16(nb + dA1, sA1 + koff); }
        __builtin_amdgcn_s_barrier();
        __builtin_amdgcn_s_setprio(1);
#pragma unroll
        for (int m = 0; m < 4; ++m) {
            accR[m] = __builtin_amdgcn_mfma_f32_32x32x16_f16(a[m], bR, accR[m], 0, 0, 0);
            accL[m] = __builtin_amdgcn_mfma_f32_32x32x16_f16(a[m], bL, accL[m], 0, 0, 0);
        }
        __builtin_amdgcn_s_setprio(0);
        __builtin_amdgcn_s_barrier();

        // ---------------- phase 1: kstep 1
#pragma unroll
        for (int m = 0; m < 4; ++m)
            a[m] = *(const f16x8*)(base + aoff + m * 2048 + 1024);
        bR = *(const f16x8*)(base + 16384 + boff + 1024);
        bL = *(const f16x8*)(base + 24576 + boff + 1024);
        if (pf) { stage16(nb + dR, sR + koff);  stage16(nb + dL, sL + koff); }
        __builtin_amdgcn_s_barrier();
        __builtin_amdgcn_s_setprio(1);
#pragma unroll
        for (int m = 0; m < 4; ++m) {
            accR[m] = __builtin_amdgcn_mfma_f32_32x32x16_f16(a[m], bR, accR[m], 0, 0, 0);
            accL[m] = __builtin_amdgcn_mfma_f32_32x32x16_f16(a[m], bL, accL[m], 0, 0, 0);
        }
        __builtin_amdgcn_s_setprio(0);
        if (t < NT - 1) {
            if (pf) asm volatile("s_waitcnt vmcnt(4)" ::: "memory");
            else    asm volatile("s_waitcnt vmcnt(0)" ::: "memory");
        }
        __builtin_amdgcn_s_barrier();

        cur = (cur == 2) ? 0 : cur + 1;
        koff += 64;
    }

    // epilogue: bias + bilinear product, fp16 out (32x32 C/D layout)
    const int col = n0 + wn * 32 + (lane & 31);
    const float brv = br[col], blv = bl[col];
#pragma unroll
    for (int m = 0; m < 4; ++m) {
        const int R0 = m0 + wm * 128 + m * 32 + 4 * (lane >> 5);
#pragma unroll
        for (int r = 0; r < 16; ++r) {
            const int row = R0 + (r & 3) + 8 * (r >> 2);
            const float rv = accR[m][r] + brv;
            const float lv = accL[m][r] + blv;
            inter[(size_t)row * HR + col] = (f16)(rv * lv);
        }
    }
}

// ---------------------------------------------------------------- GEMM2: expand
// Ain:[M,4096], Wt:[1024,4096] (NxK); E = Ain.Wt^T + be (fp16 out)
// Block 256(M) x 256(N), BK=32; 8 waves (2M x 4N); wave tile 128x64.
// LDS ring: 3 x (A 16KB + B 16KB).
__global__ __launch_bounds__(512, 2) void k_gemm_expand(
    const f16* __restrict__ Ain, const f16* __restrict__ Wt,
    const float* __restrict__ be, f16* __restrict__ E, int MT)
{
    extern __shared__ __align__(16) char smem[];
    constexpr int K = HR, NT = K / 32;
    constexpr int BUF = 32 * 1024;

    const int swz = xcd_swz(blockIdx.x, gridDim.x);
    const int mt = swz % MT, nt = swz / MT;
    const int m0 = mt * 256, n0 = nt * 256;
    const int tid = threadIdx.x;
    const int wid = tid >> 6, lane = tid & 63;
    const int wm = wid >> 2, wn = wid & 3;

    const char* sA0 = src_ptr(Ain, tid, m0,       8192);
    const char* sA1 = src_ptr(Ain, tid, m0 + 128, 8192);
    const char* sB0 = src_ptr(Wt,  tid, n0,       8192);
    const char* sB1 = src_ptr(Wt,  tid, n0 + 128, 8192);
    const int dA0 = tid * 16, dA1 = 8192 + tid * 16;
    const int dB0 = 16384 + tid * 16, dB1 = 24576 + tid * 16;

    const int aoff = wm * 8192 + lane * 16;            // + m*2048 + ks*1024
    const int boff = wn * 4096 + lane * 16;            // + n*2048 + ks*1024

    f32x16 acc[4][2] = {};

    for (int t = 0; t < 2; ++t) {
        char* b = smem + t * BUF;
        const long ko = (long)t * 64;
        stage16(b + dA0, sA0 + ko);  stage16(b + dA1, sA1 + ko);
        stage16(b + dB0, sB0 + ko);  stage16(b + dB1, sB1 + ko);
    }
    asm volatile("s_waitcnt vmcnt(4)" ::: "memory");
    __builtin_amdgcn_s_barrier();

    int cur = 0;
    long koff = 128;
    for (int t = 0; t < NT; ++t) {
        char* base = smem + cur * BUF;
        const int stg = cur ? cur - 1 : 2;
        char* nb = smem + stg * BUF;
        const bool pf = (t + 2) < NT;

        f16x8 a[4], bv[2];
        // ---------------- phase 0: kstep 0
#pragma unroll
        for (int m = 0; m < 4; ++m)
            a[m] = *(const f16x8*)(base + aoff + m * 2048);
#pragma unroll
        for (int n = 0; n < 2; ++n)
            bv[n] = *(const f16x8*)(base + 16384 + boff + n * 2048);
        if (pf) { stage16(nb + dA0, sA0 + koff);  stage16(nb + dA1, sA1 + koff); }
        __builtin_amdgcn_s_barrier();
        __builtin_amdgcn_s_setprio(1);
#pragma unroll
        for (int m = 0; m < 4; ++m)
#pragma unroll
            for (int n = 0; n < 2; ++n)
                acc[m][n] = __builtin_amdgcn_mfma_f32_32x32x16_f16(a[m], bv[n], acc[m][n], 0, 0, 0);
        __builtin_amdgcn_s_setprio(0);
        __builtin_amdgcn_s_barrier();

        // ---------------- phase 1: kstep 1
#pragma unroll
        for (int m = 0; m < 4; ++m)
            a[m] = *(const f16x8*)(base + aoff + m * 2048 + 1024);
#pragma unroll
        for (int n = 0; n < 2; ++n)
            bv[n] = *(const f16x8*)(base + 16384 + boff + n * 2048 + 1024);
        if (pf) { stage16(nb + dB0, sB0 + koff);  stage16(nb + dB1, sB1 + koff); }
        __builtin_amdgcn_s_barrier();
        __builtin_amdgcn_s_setprio(1);
#pragma unroll
        for (int m = 0; m < 4; ++m)
#pragma unroll
            for (int n = 0; n < 2; ++n)
                acc[m][n] = __builtin_amdgcn_mfma_f32_32x32x16_f16(a[m], bv[n], acc[m][n], 0, 0, 0);
        __builtin_amdgcn_s_setprio(0);
        if (t < NT - 1) {
            if (pf) asm volatile("s_waitcnt vmcnt(4)" ::: "memory");
            else    asm volatile("s_waitcnt vmcnt(0)" ::: "memory");
        }
        __builtin_amdgcn_s_barrier();

        cur = (cur == 2) ? 0 : cur + 1;
        koff += 64;
    }

#pragma unroll
    for (int n = 0; n < 2; ++n) {
        const int col = n0 + wn * 64 + n * 32 + (lane & 31);
        const float bev = be[col];
#pragma unroll
        for (int m = 0; m < 4; ++m) {
            const int R0 = m0 + wm * 128 + m * 32 + 4 * (lane >> 5);
#pragma unroll
            for (int r = 0; r < 16; ++r) {
                const int row = R0 + (r & 3) + 8 * (r >> 2);
                E[(size_t)row * D + col] = (f16)(acc[m][n][r] + bev);
            }
        }
    }
}

// ---------------------------------------------------------------- residual + LayerNorm
template <typename TR>
__global__ __launch_bounds__(256) void k_ln(
    const TR* __restrict__ X, const f16* __restrict__ Eb,
    const float* __restrict__ g, const float* __restrict__ bb,
    f16* __restrict__ Hh)
{
    const int wid = threadIdx.x >> 6, lane = threadIdx.x & 63;
    const int row = blockIdx.x * 4 + wid;
    const TR* xr = X + (size_t)row * D;
    const f16* er = Eb + (size_t)row * D;
    float v[16];
    float s = 0.f, sq = 0.f;
#pragma unroll
    for (int k = 0; k < 16; ++k) {
        const int c = lane + 64 * k;
        v[k] = (float)xr[c] + (float)er[c];
        s += v[k];
        sq += v[k] * v[k];
    }
#pragma unroll
    for (int off = 32; off; off >>= 1) {
        s += __shfl_down(s, off);
        sq += __shfl_down(sq, off);
    }
    s = __shfl(s, 0);
    sq = __shfl(sq, 0);
    const float mu = s * (1.0f / D);
    const float var = sq * (1.0f / D) - mu * mu;
    const float rs = rsqrtf(var + 1e-5f);
    f16* hh = Hh + (size_t)row * D;
#pragma unroll
    for (int k = 0; k < 16; ++k) {
        const int c = lane + 64 * k;
        const float o = (v[k] - mu) * rs * g[c] + bb[c];
        hh[c] = (f16)o;
    }
}

// ---------------------------------------------------------------- head
__global__ __launch_bounds__(256) void k_head(
    const f16* __restrict__ Hf, const float* __restrict__ Wf,
    const float* __restrict__ bf, float* __restrict__ outp)
{
    __shared__ float wfs[NOUT * D];
    for (int i = threadIdx.x; i < NOUT * D; i += 256) wfs[i] = Wf[i];
    __syncthreads();
    const int wid = threadIdx.x >> 6, lane = threadIdx.x & 63;
    const int row = blockIdx.x * 4 + wid;
    const f16* hr = Hf + (size_t)row * D;
    float hv[16];
#pragma unroll
    for (int k = 0; k < 16; ++k) hv[k] = (float)hr[lane + 64 * k];
#pragma unroll
    for (int j = 0; j < NOUT; ++j) {
        float p = 0.f;
#pragma unroll
        for (int k = 0; k < 16; ++k) p += hv[k] * wfs[j * D + lane + 64 * k];
#pragma unroll
        for (int off = 32; off; off >>= 1) p += __shfl_down(p, off);
        if (lane == 0) outp[(size_t)row * NOUT + j] = p + bf[j];
    }
}

// ---------------------------------------------------------------- launch
extern "C" void kernel_launch(void* const* d_in, const int* in_sizes, int n_in,
                              void* d_out, int out_size, void* d_ws, size_t ws_size,
                              hipStream_t stream) {
    (void)in_sizes; (void)n_in; (void)out_size;
    const float* x   = (const float*)d_in[0];
    const float* wr1 = (const float*)d_in[1];
    const float* br1 = (const float*)d_in[2];
    const float* wl1 = (const float*)d_in[3];
    const float* bl1 = (const float*)d_in[4];
    const float* we1 = (const float*)d_in[5];
    const float* be1 = (const float*)d_in[6];
    const float* g1  = (const float*)d_in[7];
    const float* b1  = (const float*)d_in[8];
    const float* wr2 = (const float*)d_in[9];
    const float* br2 = (const float*)d_in[10];
    const float* wl2 = (const float*)d_in[11];
    const float* bl2 = (const float*)d_in[12];
    const float* we2 = (const float*)d_in[13];
    const float* be2 = (const float*)d_in[14];
    const float* g2  = (const float*)d_in[15];
    const float* b2  = (const float*)d_in[16];
    const float* wf  = (const float*)d_in[17];
    const float* bf  = (const float*)d_in[18];
    float* outp = (float*)d_out;

    constexpr size_t SZ_W16 = (size_t)HR * D * sizeof(f16);
    constexpr size_t SZ_A16 = (size_t)BATCH * D * sizeof(f16);
    constexpr int SMEM = 3 * 32 * 1024;

    hipFuncSetAttribute((const void*)k_gemm_dual,   hipFuncAttributeMaxDynamicSharedMemorySize, SMEM);
    hipFuncSetAttribute((const void*)k_gemm_expand, hipFuncAttributeMaxDynamicSharedMemorySize, SMEM);

    char* p = (char*)d_ws;
    f16* wrh = (f16*)p; p += SZ_W16;
    f16* wlh = (f16*)p; p += SZ_W16;
    f16* weh = (f16*)p; p += SZ_W16;
    f16* xh  = (f16*)p; p += SZ_A16;
    f16* h1h = (f16*)p; p += SZ_A16;
    f16* Eh  = (f16*)p; p += SZ_A16;
    f16* interh = (f16*)p;
    const size_t base = (size_t)(p - (char*)d_ws);
    const size_t avail = ws_size > base ? ws_size - base : 0;

    int CH = 1024;
    if ((size_t)16384 * HR * sizeof(f16) <= avail) CH = 16384;
    else if ((size_t)8192 * HR * sizeof(f16) <= avail) CH = 8192;
    else if ((size_t)4096 * HR * sizeof(f16) <= avail) CH = 4096;
    else if ((size_t)2048 * HR * sizeof(f16) <= avail) CH = 2048;

    f16* h2h = xh;
    const int nch = BATCH / CH;
    const int MT = CH / 256;
    const int gDual = MT * (HR / 128);
    const int gExp  = MT * (D / 256);

    k_f32_to_f16<<<2048, 256, 0, stream>>>(x,   xh,  BATCH * D / 4);
    k_f32_to_f16<<<1024, 256, 0, stream>>>(wr1, wrh, HR * D / 4);
    k_f32_to_f16<<<1024, 256, 0, stream>>>(wl1, wlh, HR * D / 4);
    k_f32_to_f16<<<1024, 256, 0, stream>>>(we1, weh, HR * D / 4);

    for (int c = 0; c < nch; ++c) {
        k_gemm_dual<<<gDual, 512, SMEM, stream>>>(xh + (size_t)c * CH * D, wrh, wlh, br1, bl1, interh, MT);
        k_gemm_expand<<<gExp, 512, SMEM, stream>>>(interh, weh, be1, Eh + (size_t)c * CH * D, MT);
    }
    k_ln<float><<<BATCH / 4, 256, 0, stream>>>(x, Eh, g1, b1, h1h);

    k_f32_to_f16<<<1024, 256, 0, stream>>>(wr2, wrh, HR * D / 4);
    k_f32_to_f16<<<1024, 256, 0, stream>>>(wl2, wlh, HR * D / 4);
    k_f32_to_f16<<<1024, 256, 0, stream>>>(we2, weh, HR * D / 4);

    for (int c = 0; c < nch; ++c) {
        k_gemm_dual<<<gDual, 512, SMEM, stream>>>(h1h + (size_t)c * CH * D, wrh, wlh, br2, bl2, interh, MT);
        k_gemm_expand<<<gExp, 512, SMEM, stream>>>(interh, weh, be2, Eh + (size_t)c * CH * D, MT);
    }
    k_ln<f16><<<BATCH / 4, 256, 0, stream>>>(h1h, Eh, g2, b2, h2h);

    k_head<<<BATCH / 4, 256, 0, stream>>>(h2h, wf, bf, outp);
}

// Round 6
// 874.153 us; speedup vs baseline: 1.1835x; 1.1835x over previous
//
#include <hip/hip_runtime.h>
#include <hip/hip_fp16.h>

#define DEV static __device__ __forceinline__

typedef _Float16 f16;
typedef _Float16 f16x8 __attribute__((ext_vector_type(8)));
typedef _Float16 f16x4 __attribute__((ext_vector_type(4)));
typedef float f32x4 __attribute__((ext_vector_type(4)));

constexpr int BATCH = 16384;
constexpr int D = 1024;
constexpr int HR = 4096;
constexpr int NOUT = 10;

// ---------------------------------------------------------------- converts
__global__ void k_f32_to_f16(const float* __restrict__ src, f16* __restrict__ dst, int n4) {
    int i = blockIdx.x * blockDim.x + threadIdx.x;
    int stride = gridDim.x * blockDim.x;
    for (; i < n4; i += stride) {
        float4 v = reinterpret_cast<const float4*>(src)[i];
        f16x4 h;
        h[0] = (f16)v.x; h[1] = (f16)v.y; h[2] = (f16)v.z; h[3] = (f16)v.w;
        reinterpret_cast<f16x4*>(dst)[i] = h;
    }
}

// ---------------------------------------------------------------- helpers
DEV void stage16(void* lds, const void* g) {
    __builtin_amdgcn_global_load_lds(
        (const __attribute__((address_space(1))) void*)g,
        (__attribute__((address_space(3))) void*)lds,
        16, 0, 0);
}

DEV int xcd_swz(int bid, int nwg) {        // nwg % 8 == 0 in all our grids
    const int cpx = nwg >> 3;
    return (bid & 7) * cpx + (bid >> 3);
}

#define VMCNT(n) asm volatile("s_waitcnt vmcnt(" #n ")" ::: "memory")
#define BAR()    __builtin_amdgcn_s_barrier()
#define PRIO(p)  __builtin_amdgcn_s_setprio(p)

// ---------------------------------------------------------------- GEMM1: dual projection + bilinear fuse
// Xh:[M,1024], Wr/Wl:[4096,1024] (NxK); inter[b,n] = (X.Wr[n]+br)*(X.Wl[n]+bl)
// Block 256M x 128N-dual, BK=64; 8 waves (2M x 4N); wave 128M x 32N for R AND L.
// 4 phases/K-tile (quadrant walk: (mi0,R),(mi0,L),(mi1,R),(mi1,L)); per tile a wave
// ds_reads A-half once (8 b128) and bR/bL once (4 each) = 12KB per 128 MFMA-FLOP-tile.
// LDS: 2 bufs x (A 32KB + R 16KB + L 16KB) = 128KB.  Counted vmcnt(4), XOR-swizzled rows.
__global__ __launch_bounds__(512, 2) void k_gemm_dual(
    const f16* __restrict__ Xh, const f16* __restrict__ Wr, const f16* __restrict__ Wl,
    const float* __restrict__ br, const float* __restrict__ bl,
    f16* __restrict__ inter, int MT)
{
    extern __shared__ __align__(16) char smem[];
    constexpr int NT = 16;                 // 1024 / 64
    constexpr int BUF = 65536;
    constexpr int OA = 0, OR = 32768, OL = 49152;

    const int swzb = xcd_swz(blockIdx.x, gridDim.x);
    const int mt = swzb % MT, nt = swzb / MT;
    const int m0 = mt * 256, n0 = nt * 128;
    const int tid = threadIdx.x;
    const int lane = tid & 63, wid = tid >> 6;
    const int wm = wid >> 2, wn = wid & 3;
    const int fr = lane & 15, fq = lane >> 4;
    const int xs = (fr & 7) << 4;
    const int dst = tid * 16;

    // stage sources: 8 units of 8KB; unit covers LDS rows u*64..u*64+63 of its region.
    // thread -> ldsRow = u*64 + (tid>>3), linear col (tid&7)*16, inverse-swizzled.
    const int lr = tid >> 3;
    const int cb = ((tid & 7) << 4) ^ ((lr & 7) << 4);
    // A LDS row order: [mi][wm][r]  ->  global row wm*128 + mi*64 + r
    const char* pA0 = (const char*)Xh + (size_t)(m0 + lr)       * 2048 + cb;  // mi0,wm0
    const char* pA1 = (const char*)Xh + (size_t)(m0 + 128 + lr) * 2048 + cb;  // mi0,wm1
    const char* pA2 = (const char*)Xh + (size_t)(m0 + 64 + lr)  * 2048 + cb;  // mi1,wm0
    const char* pA3 = (const char*)Xh + (size_t)(m0 + 192 + lr) * 2048 + cb;  // mi1,wm1
    const char* pR0 = (const char*)Wr + (size_t)(n0 + lr)       * 2048 + cb;
    const char* pR1 = (const char*)Wr + (size_t)(n0 + 64 + lr)  * 2048 + cb;
    const char* pL0 = (const char*)Wl + (size_t)(n0 + lr)       * 2048 + cb;
    const char* pL1 = (const char*)Wl + (size_t)(n0 + 64 + lr)  * 2048 + cb;

#define D_AOFF(mi,mf,ks) (OA + ((mi)*128 + wm*64 + (mf)*16 + fr)*128 + ((((ks)*64) + fq*16) ^ xs))
#define D_ROFF(nf,ks)    (OR + (wn*32 + (nf)*16 + fr)*128 + ((((ks)*64) + fq*16) ^ xs))
#define D_LOFF(nf,ks)    (OL + (wn*32 + (nf)*16 + fr)*128 + ((((ks)*64) + fq*16) ^ xs))

    f16x8 a[4][2], bR[2][2], bL[2][2];
    f32x4 accR[8][2] = {};
    f32x4 accL[8][2] = {};

    // prologue: stage tile 0 in need-order
    stage16(smem + OA + dst, pA0);          stage16(smem + OA + 8192 + dst, pA1);
    stage16(smem + OR + dst, pR0);          stage16(smem + OR + 8192 + dst, pR1);
    stage16(smem + OL + dst, pL0);          stage16(smem + OL + 8192 + dst, pL1);
    stage16(smem + OA + 16384 + dst, pA2);  stage16(smem + OA + 24576 + dst, pA3);
    VMCNT(4);
    BAR();

    long ko = 128;
    for (int t = 0; t < NT; ++t) {
        char* base = smem + (t & 1) * BUF;
        char* nb   = smem + ((t & 1) ^ 1) * BUF;
        const bool pf = (t + 1) < NT;

        // ---- p1: (mi0, R)
#pragma unroll
        for (int mf = 0; mf < 4; ++mf)
#pragma unroll
            for (int ks = 0; ks < 2; ++ks)
                a[mf][ks] = *(const f16x8*)(base + D_AOFF(0, mf, ks));
#pragma unroll
        for (int nf = 0; nf < 2; ++nf)
#pragma unroll
            for (int ks = 0; ks < 2; ++ks)
                bR[nf][ks] = *(const f16x8*)(base + D_ROFF(nf, ks));
        if (pf) { stage16(nb + OA + dst, pA0 + ko); stage16(nb + OA + 8192 + dst, pA1 + ko); }
        BAR();
        PRIO(1);
#pragma unroll
        for (int mf = 0; mf < 4; ++mf)
#pragma unroll
            for (int nf = 0; nf < 2; ++nf)
#pragma unroll
                for (int ks = 0; ks < 2; ++ks)
                    accR[mf][nf] = __builtin_amdgcn_mfma_f32_16x16x32_f16(a[mf][ks], bR[nf][ks], accR[mf][nf], 0, 0, 0);
        PRIO(0);
        if (pf) { VMCNT(4); } else { VMCNT(2); }   // publish L0L1
        BAR();

        // ---- p2: (mi0, L)
#pragma unroll
        for (int nf = 0; nf < 2; ++nf)
#pragma unroll
            for (int ks = 0; ks < 2; ++ks)
                bL[nf][ks] = *(const f16x8*)(base + D_LOFF(nf, ks));
        if (pf) { stage16(nb + OR + dst, pR0 + ko); stage16(nb + OR + 8192 + dst, pR1 + ko); }
        BAR();
        PRIO(1);
#pragma unroll
        for (int mf = 0; mf < 4; ++mf)
#pragma unroll
            for (int nf = 0; nf < 2; ++nf)
#pragma unroll
                for (int ks = 0; ks < 2; ++ks)
                    accL[mf][nf] = __builtin_amdgcn_mfma_f32_16x16x32_f16(a[mf][ks], bL[nf][ks], accL[mf][nf], 0, 0, 0);
        PRIO(0);
        if (pf) { VMCNT(4); } else { VMCNT(0); }   // publish A2A3
        BAR();

        // ---- p3: (mi1, R)
#pragma unroll
        for (int mf = 0; mf < 4; ++mf)
#pragma unroll
            for (int ks = 0; ks < 2; ++ks)
                a[mf][ks] = *(const f16x8*)(base + D_AOFF(1, mf, ks));
        if (pf) { stage16(nb + OL + dst, pL0 + ko); stage16(nb + OL + 8192 + dst, pL1 + ko); }
        BAR();
        PRIO(1);
#pragma unroll
        for (int mf = 0; mf < 4; ++mf)
#pragma unroll
            for (int nf = 0; nf < 2; ++nf)
#pragma unroll
                for (int ks = 0; ks < 2; ++ks)
                    accR[4 + mf][nf] = __builtin_amdgcn_mfma_f32_16x16x32_f16(a[mf][ks], bR[nf][ks], accR[4 + mf][nf], 0, 0, 0);
        PRIO(0);
        BAR();

        // ---- p4: (mi1, L)
        if (pf) { stage16(nb + OA + 16384 + dst, pA2 + ko); stage16(nb + OA + 24576 + dst, pA3 + ko); }
        BAR();
        PRIO(1);
#pragma unroll
        for (int mf = 0; mf < 4; ++mf)
#pragma unroll
            for (int nf = 0; nf < 2; ++nf)
#pragma unroll
                for (int ks = 0; ks < 2; ++ks)
                    accL[4 + mf][nf] = __builtin_amdgcn_mfma_f32_16x16x32_f16(a[mf][ks], bL[nf][ks], accL[4 + mf][nf], 0, 0, 0);
        PRIO(0);
        if (pf) { VMCNT(4); }                      // publish next A0A1,R0R1
        BAR();

        ko += 128;
    }

    // epilogue: bias + bilinear product, fp16 out
#pragma unroll
    for (int nf = 0; nf < 2; ++nf) {
        const int gc = n0 + wn * 32 + nf * 16 + fr;
        const float brv = br[gc], blv = bl[gc];
#pragma unroll
        for (int mi = 0; mi < 2; ++mi)
#pragma unroll
            for (int mf = 0; mf < 4; ++mf) {
                const int gr0 = m0 + wm * 128 + mi * 64 + mf * 16 + fq * 4;
#pragma unroll
                for (int j = 0; j < 4; ++j) {
                    const float rv = accR[mi * 4 + mf][nf][j] + brv;
                    const float lv = accL[mi * 4 + mf][nf][j] + blv;
                    inter[(size_t)(gr0 + j) * HR + gc] = (f16)(rv * lv);
                }
            }
    }
#undef D_AOFF
#undef D_ROFF
#undef D_LOFF
}

// ---------------------------------------------------------------- GEMM2: expand
// Ain:[M,4096], Wt:[1024,4096] (NxK); E = Ain.Wt^T + be (fp16 out)
// Block 256M x 256N, BK=64; 8 waves (2M x 4N); wave 128x64, quadrant walk
// (mi0,n0),(mi0,n1),(mi1,n0),(mi1,n1).  LDS: 2 x (A 32KB + B 32KB) = 128KB.
__global__ __launch_bounds__(512, 2) void k_gemm_expand(
    const f16* __restrict__ Ain, const f16* __restrict__ Wt,
    const float* __restrict__ be, f16* __restrict__ E, int MT)
{
    extern __shared__ __align__(16) char smem[];
    constexpr int NT = 64;                 // 4096 / 64
    constexpr int BUF = 65536;
    constexpr int OA = 0, OB = 32768;

    const int swzb = xcd_swz(blockIdx.x, gridDim.x);
    const int mt = swzb % MT, nt = swzb / MT;
    const int m0 = mt * 256, n0 = nt * 256;
    const int tid = threadIdx.x;
    const int lane = tid & 63, wid = tid >> 6;
    const int wm = wid >> 2, wn = wid & 3;
    const int fr = lane & 15, fq = lane >> 4;
    const int xs = (fr & 7) << 4;
    const int dst = tid * 16;

    const int lr = tid >> 3;
    const int cb = ((tid & 7) << 4) ^ ((lr & 7) << 4);
    // A LDS rows [mi][wm][r] -> global row wm*128 + mi*64 + r
    const char* pA0 = (const char*)Ain + (size_t)(m0 + lr)       * 8192 + cb;
    const char* pA1 = (const char*)Ain + (size_t)(m0 + 128 + lr) * 8192 + cb;
    const char* pA2 = (const char*)Ain + (size_t)(m0 + 64 + lr)  * 8192 + cb;
    const char* pA3 = (const char*)Ain + (size_t)(m0 + 192 + lr) * 8192 + cb;
    // B LDS rows [ni][wn][r] (r<32) -> global col wn*64 + ni*32 + r
    const int r5 = lr & 31, wn2 = lr >> 5;
    const char* pB0 = (const char*)Wt + (size_t)(n0 + wn2 * 64 + r5)        * 8192 + cb; // ni0, wn 0-1
    const char* pB1 = (const char*)Wt + (size_t)(n0 + (2 + wn2) * 64 + r5)  * 8192 + cb; // ni0, wn 2-3
    const char* pB2 = (const char*)Wt + (size_t)(n0 + wn2 * 64 + 32 + r5)       * 8192 + cb; // ni1, wn 0-1
    const char* pB3 = (const char*)Wt + (size_t)(n0 + (2 + wn2) * 64 + 32 + r5) * 8192 + cb; // ni1, wn 2-3

#define E_AOFF(mi,mf,ks) (OA + ((mi)*128 + wm*64 + (mf)*16 + fr)*128 + ((((ks)*64) + fq*16) ^ xs))
#define E_BOFF(ni,nf,ks) (OB + ((ni)*128 + wn*32 + (nf)*16 + fr)*128 + ((((ks)*64) + fq*16) ^ xs))

    f16x8 a[4][2], b0[2][2], b1[2][2];
    f32x4 acc[8][4] = {};

    // prologue: stage tile 0 in need-order: A0A1, B0B1(ni0), B2B3(ni1), A2A3
    stage16(smem + OA + dst, pA0);          stage16(smem + OA + 8192 + dst, pA1);
    stage16(smem + OB + dst, pB0);          stage16(smem + OB + 8192 + dst, pB1);
    stage16(smem + OB + 16384 + dst, pB2);  stage16(smem + OB + 24576 + dst, pB3);
    stage16(smem + OA + 16384 + dst, pA2);  stage16(smem + OA + 24576 + dst, pA3);
    VMCNT(4);
    BAR();

    long ko = 128;
    for (int t = 0; t < NT; ++t) {
        char* base = smem + (t & 1) * BUF;
        char* nb   = smem + ((t & 1) ^ 1) * BUF;
        const bool pf = (t + 1) < NT;

        // ---- p1: (mi0, ni0)
#pragma unroll
        for (int mf = 0; mf < 4; ++mf)
#pragma unroll
            for (int ks = 0; ks < 2; ++ks)
                a[mf][ks] = *(const f16x8*)(base + E_AOFF(0, mf, ks));
#pragma unroll
        for (int nf = 0; nf < 2; ++nf)
#pragma unroll
            for (int ks = 0; ks < 2; ++ks)
                b0[nf][ks] = *(const f16x8*)(base + E_BOFF(0, nf, ks));
        if (pf) { stage16(nb + OA + dst, pA0 + ko); stage16(nb + OA + 8192 + dst, pA1 + ko); }
        BAR();
        PRIO(1);
#pragma unroll
        for (int mf = 0; mf < 4; ++mf)
#pragma unroll
            for (int nf = 0; nf < 2; ++nf)
#pragma unroll
                for (int ks = 0; ks < 2; ++ks)
                    acc[mf][nf] = __builtin_amdgcn_mfma_f32_16x16x32_f16(a[mf][ks], b0[nf][ks], acc[mf][nf], 0, 0, 0);
        PRIO(0);
        if (pf) { VMCNT(4); } else { VMCNT(2); }   // publish B2B3 (ni1)
        BAR();

        // ---- p2: (mi0, ni1)
#pragma unroll
        for (int nf = 0; nf < 2; ++nf)
#pragma unroll
            for (int ks = 0; ks < 2; ++ks)
                b1[nf][ks] = *(const f16x8*)(base + E_BOFF(1, nf, ks));
        if (pf) { stage16(nb + OB + dst, pB0 + ko); stage16(nb + OB + 8192 + dst, pB1 + ko); }
        BAR();
        PRIO(1);
#pragma unroll
        for (int mf = 0; mf < 4; ++mf)
#pragma unroll
            for (int nf = 0; nf < 2; ++nf)
#pragma unroll
                for (int ks = 0; ks < 2; ++ks)
                    acc[mf][2 + nf] = __builtin_amdgcn_mfma_f32_16x16x32_f16(a[mf][ks], b1[nf][ks], acc[mf][2 + nf], 0, 0, 0);
        PRIO(0);
        if (pf) { VMCNT(4); } else { VMCNT(0); }   // publish A2A3
        BAR();

        // ---- p3: (mi1, ni0)
#pragma unroll
        for (int mf = 0; mf < 4; ++mf)
#pragma unroll
            for (int ks = 0; ks < 2; ++ks)
                a[mf][ks] = *(const f16x8*)(base + E_AOFF(1, mf, ks));
        if (pf) { stage16(nb + OB + 16384 + dst, pB2 + ko); stage16(nb + OB + 24576 + dst, pB3 + ko); }
        BAR();
        PRIO(1);
#pragma unroll
        for (int mf = 0; mf < 4; ++mf)
#pragma unroll
            for (int nf = 0; nf < 2; ++nf)
#pragma unroll
                for (int ks = 0; ks < 2; ++ks)
                    acc[4 + mf][nf] = __builtin_amdgcn_mfma_f32_16x16x32_f16(a[mf][ks], b0[nf][ks], acc[4 + mf][nf], 0, 0, 0);
        PRIO(0);
        BAR();

        // ---- p4: (mi1, ni1)
        if (pf) { stage16(nb + OA + 16384 + dst, pA2 + ko); stage16(nb + OA + 24576 + dst, pA3 + ko); }
        BAR();
        PRIO(1);
#pragma unroll
        for (int mf = 0; mf < 4; ++mf)
#pragma unroll
            for (int nf = 0; nf < 2; ++nf)
#pragma unroll
                for (int ks = 0; ks < 2; ++ks)
                    acc[4 + mf][2 + nf] = __builtin_amdgcn_mfma_f32_16x16x32_f16(a[mf][ks], b1[nf][ks], acc[4 + mf][2 + nf], 0, 0, 0);
        PRIO(0);
        if (pf) { VMCNT(4); }                      // publish next A0A1,B0B1
        BAR();

        ko += 128;
    }

#pragma unroll
    for (int ni = 0; ni < 2; ++ni)
#pragma unroll
        for (int nf = 0; nf < 2; ++nf) {
            const int gc = n0 + wn * 64 + ni * 32 + nf * 16 + fr;
            const float bev = be[gc];
#pragma unroll
            for (int mi = 0; mi < 2; ++mi)
#pragma unroll
                for (int mf = 0; mf < 4; ++mf) {
                    const int gr0 = m0 + wm * 128 + mi * 64 + mf * 16 + fq * 4;
#pragma unroll
                    for (int j = 0; j < 4; ++j)
                        E[(size_t)(gr0 + j) * D + gc] = (f16)(acc[mi * 4 + mf][ni * 2 + nf][j] + bev);
                }
        }
#undef E_AOFF
#undef E_BOFF
}

// ---------------------------------------------------------------- residual + LayerNorm
template <typename TR>
__global__ __launch_bounds__(256) void k_ln(
    const TR* __restrict__ X, const f16* __restrict__ Eb,
    const float* __restrict__ g, const float* __restrict__ bb,
    f16* __restrict__ Hh)
{
    const int wid = threadIdx.x >> 6, lane = threadIdx.x & 63;
    const int row = blockIdx.x * 4 + wid;
    const TR* xr = X + (size_t)row * D;
    const f16* er = Eb + (size_t)row * D;
    float v[16];
    float s = 0.f, sq = 0.f;
#pragma unroll
    for (int k = 0; k < 16; ++k) {
        const int c = lane + 64 * k;
        v[k] = (float)xr[c] + (float)er[c];
        s += v[k];
        sq += v[k] * v[k];
    }
#pragma unroll
    for (int off = 32; off; off >>= 1) {
        s += __shfl_down(s, off);
        sq += __shfl_down(sq, off);
    }
    s = __shfl(s, 0);
    sq = __shfl(sq, 0);
    const float mu = s * (1.0f / D);
    const float var = sq * (1.0f / D) - mu * mu;
    const float rs = rsqrtf(var + 1e-5f);
    f16* hh = Hh + (size_t)row * D;
#pragma unroll
    for (int k = 0; k < 16; ++k) {
        const int c = lane + 64 * k;
        const float o = (v[k] - mu) * rs * g[c] + bb[c];
        hh[c] = (f16)o;
    }
}

// ---------------------------------------------------------------- head
__global__ __launch_bounds__(256) void k_head(
    const f16* __restrict__ Hf, const float* __restrict__ Wf,
    const float* __restrict__ bf, float* __restrict__ outp)
{
    __shared__ float wfs[NOUT * D];
    for (int i = threadIdx.x; i < NOUT * D; i += 256) wfs[i] = Wf[i];
    __syncthreads();
    const int wid = threadIdx.x >> 6, lane = threadIdx.x & 63;
    const int row = blockIdx.x * 4 + wid;
    const f16* hr = Hf + (size_t)row * D;
    float hv[16];
#pragma unroll
    for (int k = 0; k < 16; ++k) hv[k] = (float)hr[lane + 64 * k];
#pragma unroll
    for (int j = 0; j < NOUT; ++j) {
        float p = 0.f;
#pragma unroll
        for (int k = 0; k < 16; ++k) p += hv[k] * wfs[j * D + lane + 64 * k];
#pragma unroll
        for (int off = 32; off; off >>= 1) p += __shfl_down(p, off);
        if (lane == 0) outp[(size_t)row * NOUT + j] = p + bf[j];
    }
}

// ---------------------------------------------------------------- launch
extern "C" void kernel_launch(void* const* d_in, const int* in_sizes, int n_in,
                              void* d_out, int out_size, void* d_ws, size_t ws_size,
                              hipStream_t stream) {
    (void)in_sizes; (void)n_in; (void)out_size;
    const float* x   = (const float*)d_in[0];
    const float* wr1 = (const float*)d_in[1];
    const float* br1 = (const float*)d_in[2];
    const float* wl1 = (const float*)d_in[3];
    const float* bl1 = (const float*)d_in[4];
    const float* we1 = (const float*)d_in[5];
    const float* be1 = (const float*)d_in[6];
    const float* g1  = (const float*)d_in[7];
    const float* b1  = (const float*)d_in[8];
    const float* wr2 = (const float*)d_in[9];
    const float* br2 = (const float*)d_in[10];
    const float* wl2 = (const float*)d_in[11];
    const float* bl2 = (const float*)d_in[12];
    const float* we2 = (const float*)d_in[13];
    const float* be2 = (const float*)d_in[14];
    const float* g2  = (const float*)d_in[15];
    const float* b2  = (const float*)d_in[16];
    const float* wf  = (const float*)d_in[17];
    const float* bf  = (const float*)d_in[18];
    float* outp = (float*)d_out;

    constexpr size_t SZ_W16 = (size_t)HR * D * sizeof(f16);
    constexpr size_t SZ_A16 = (size_t)BATCH * D * sizeof(f16);
    constexpr int SMEM = 2 * 65536;

    hipFuncSetAttribute((const void*)k_gemm_dual,   hipFuncAttributeMaxDynamicSharedMemorySize, SMEM);
    hipFuncSetAttribute((const void*)k_gemm_expand, hipFuncAttributeMaxDynamicSharedMemorySize, SMEM);

    char* p = (char*)d_ws;
    f16* wrh = (f16*)p; p += SZ_W16;
    f16* wlh = (f16*)p; p += SZ_W16;
    f16* weh = (f16*)p; p += SZ_W16;
    f16* xh  = (f16*)p; p += SZ_A16;
    f16* h1h = (f16*)p; p += SZ_A16;
    f16* Eh  = (f16*)p; p += SZ_A16;
    f16* interh = (f16*)p;
    const size_t base = (size_t)(p - (char*)d_ws);
    const size_t avail = ws_size > base ? ws_size - base : 0;

    int CH = 2048;
    if ((size_t)16384 * HR * sizeof(f16) <= avail) CH = 16384;
    else if ((size_t)8192 * HR * sizeof(f16) <= avail) CH = 8192;
    else if ((size_t)4096 * HR * sizeof(f16) <= avail) CH = 4096;

    f16* h2h = xh;
    const int nch = BATCH / CH;
    const int MT = CH / 256;
    const int gDual = MT * (HR / 128);
    const int gExp  = MT * (D / 256);

    k_f32_to_f16<<<2048, 256, 0, stream>>>(x,   xh,  BATCH * D / 4);
    k_f32_to_f16<<<1024, 256, 0, stream>>>(wr1, wrh, HR * D / 4);
    k_f32_to_f16<<<1024, 256, 0, stream>>>(wl1, wlh, HR * D / 4);
    k_f32_to_f16<<<1024, 256, 0, stream>>>(we1, weh, HR * D / 4);

    for (int c = 0; c < nch; ++c) {
        k_gemm_dual<<<gDual, 512, SMEM, stream>>>(xh + (size_t)c * CH * D, wrh, wlh, br1, bl1, interh, MT);
        k_gemm_expand<<<gExp, 512, SMEM, stream>>>(interh, weh, be1, Eh + (size_t)c * CH * D, MT);
    }
    k_ln<float><<<BATCH / 4, 256, 0, stream>>>(x, Eh, g1, b1, h1h);

    k_f32_to_f16<<<1024, 256, 0, stream>>>(wr2, wrh, HR * D / 4);
    k_f32_to_f16<<<1024, 256, 0, stream>>>(wl2, wlh, HR * D / 4);
    k_f32_to_f16<<<1024, 256, 0, stream>>>(we2, weh, HR * D / 4);

    for (int c = 0; c < nch; ++c) {
        k_gemm_dual<<<gDual, 512, SMEM, stream>>>(h1h + (size_t)c * CH * D, wrh, wlh, br2, bl2, interh, MT);
        k_gemm_expand<<<gExp, 512, SMEM, stream>>>(interh, weh, be2, Eh + (size_t)c * CH * D, MT);
    }
    k_ln<f16><<<BATCH / 4, 256, 0, stream>>>(h1h, Eh, g2, b2, h2h);

    k_head<<<BATCH / 4, 256, 0, stream>>>(h2h, wf, bf, outp);
}

// Round 7
// 856.857 us; speedup vs baseline: 1.2074x; 1.0202x over previous
//
#include <hip/hip_runtime.h>
#include <hip/hip_fp16.h>

#define DEV static __device__ __forceinline__

typedef _Float16 f16;
typedef _Float16 f16x8 __attribute__((ext_vector_type(8)));
typedef _Float16 f16x4 __attribute__((ext_vector_type(4)));
typedef float f32x4 __attribute__((ext_vector_type(4)));

constexpr int BATCH = 16384;
constexpr int D = 1024;
constexpr int HR = 4096;
constexpr int NOUT = 10;

// ---------------------------------------------------------------- fused converts (4 segments, any may be empty)
__global__ void k_conv4(const float* __restrict__ s0, f16* __restrict__ d0, int n0,
                        const float* __restrict__ s1, f16* __restrict__ d1, int n1,
                        const float* __restrict__ s2, f16* __restrict__ d2, int n2,
                        const float* __restrict__ s3, f16* __restrict__ d3, int n3) {
    int i = blockIdx.x * blockDim.x + threadIdx.x;
    const int st = gridDim.x * blockDim.x;
    const int tot = n0 + n1 + n2 + n3;
    for (; i < tot; i += st) {
        const float* s; f16* d; int j = i;
        if (j < n0) { s = s0; d = d0; }
        else {
            j -= n0;
            if (j < n1) { s = s1; d = d1; }
            else {
                j -= n1;
                if (j < n2) { s = s2; d = d2; }
                else { j -= n2; s = s3; d = d3; }
            }
        }
        float4 v = reinterpret_cast<const float4*>(s)[j];
        f16x4 h;
        h[0] = (f16)v.x; h[1] = (f16)v.y; h[2] = (f16)v.z; h[3] = (f16)v.w;
        reinterpret_cast<f16x4*>(d)[j] = h;
    }
}

// ---------------------------------------------------------------- helpers
DEV void stage16(void* lds, const void* g) {
    __builtin_amdgcn_global_load_lds(
        (const __attribute__((address_space(1))) void*)g,
        (__attribute__((address_space(3))) void*)lds,
        16, 0, 0);
}

DEV int xcd_swz(int bid, int nwg) {        // nwg % 8 == 0 in all our grids
    const int cpx = nwg >> 3;
    return (bid & 7) * cpx + (bid >> 3);
}

#define VMCNT(n) asm volatile("s_waitcnt vmcnt(" #n ")" ::: "memory")
#define BAR()    __builtin_amdgcn_s_barrier()
#define PRIO(p)  __builtin_amdgcn_s_setprio(p)

// ---------------------------------------------------------------- GEMM1: dual projection + bilinear fuse
// Block 256M x 128N-dual, BK=64; 8 waves (2M x 4N); wave 128M x 32N for R AND L.
// 4 phases/K-tile (quadrant walk); ONE barrier per phase (end), counted vmcnt(4).
// LDS: 2 bufs x (A 32KB + R 16KB + L 16KB) = 128KB.
__global__ __launch_bounds__(512, 2) void k_gemm_dual(
    const f16* __restrict__ Xh, const f16* __restrict__ Wr, const f16* __restrict__ Wl,
    const float* __restrict__ br, const float* __restrict__ bl,
    f16* __restrict__ inter, int MT)
{
    extern __shared__ __align__(16) char smem[];
    constexpr int NT = 16;                 // 1024 / 64
    constexpr int BUF = 65536;
    constexpr int OA = 0, OR = 32768, OL = 49152;

    const int swzb = xcd_swz(blockIdx.x, gridDim.x);
    const int mt = swzb % MT, nt = swzb / MT;
    const int m0 = mt * 256, n0 = nt * 128;
    const int tid = threadIdx.x;
    const int lane = tid & 63, wid = tid >> 6;
    const int wm = wid >> 2, wn = wid & 3;
    const int fr = lane & 15, fq = lane >> 4;
    const int xs = (fr & 7) << 4;
    const int dst = tid * 16;

    const int lr = tid >> 3;
    const int cb = ((tid & 7) << 4) ^ ((lr & 7) << 4);
    const char* pA0 = (const char*)Xh + (size_t)(m0 + lr)       * 2048 + cb;  // mi0,wm0
    const char* pA1 = (const char*)Xh + (size_t)(m0 + 128 + lr) * 2048 + cb;  // mi0,wm1
    const char* pA2 = (const char*)Xh + (size_t)(m0 + 64 + lr)  * 2048 + cb;  // mi1,wm0
    const char* pA3 = (const char*)Xh + (size_t)(m0 + 192 + lr) * 2048 + cb;  // mi1,wm1
    const char* pR0 = (const char*)Wr + (size_t)(n0 + lr)       * 2048 + cb;
    const char* pR1 = (const char*)Wr + (size_t)(n0 + 64 + lr)  * 2048 + cb;
    const char* pL0 = (const char*)Wl + (size_t)(n0 + lr)       * 2048 + cb;
    const char* pL1 = (const char*)Wl + (size_t)(n0 + 64 + lr)  * 2048 + cb;

#define D_AOFF(mi,mf,ks) (OA + ((mi)*128 + wm*64 + (mf)*16 + fr)*128 + ((((ks)*64) + fq*16) ^ xs))
#define D_ROFF(nf,ks)    (OR + (wn*32 + (nf)*16 + fr)*128 + ((((ks)*64) + fq*16) ^ xs))
#define D_LOFF(nf,ks)    (OL + (wn*32 + (nf)*16 + fr)*128 + ((((ks)*64) + fq*16) ^ xs))

    f16x8 a[4][2], bR[2][2], bL[2][2];
    f32x4 accR[8][2] = {};
    f32x4 accL[8][2] = {};

    // prologue: stage tile 0 in need-order
    stage16(smem + OA + dst, pA0);          stage16(smem + OA + 8192 + dst, pA1);
    stage16(smem + OR + dst, pR0);          stage16(smem + OR + 8192 + dst, pR1);
    stage16(smem + OL + dst, pL0);          stage16(smem + OL + 8192 + dst, pL1);
    stage16(smem + OA + 16384 + dst, pA2);  stage16(smem + OA + 24576 + dst, pA3);
    VMCNT(4);
    BAR();

    long ko = 128;
    for (int t = 0; t < NT; ++t) {
        char* base = smem + (t & 1) * BUF;
        char* nb   = smem + ((t & 1) ^ 1) * BUF;
        const bool pf = (t + 1) < NT;

        // ---- p1: (mi0, R)
#pragma unroll
        for (int mf = 0; mf < 4; ++mf)
#pragma unroll
            for (int ks = 0; ks < 2; ++ks)
                a[mf][ks] = *(const f16x8*)(base + D_AOFF(0, mf, ks));
#pragma unroll
        for (int nf = 0; nf < 2; ++nf)
#pragma unroll
            for (int ks = 0; ks < 2; ++ks)
                bR[nf][ks] = *(const f16x8*)(base + D_ROFF(nf, ks));
        if (pf) { stage16(nb + OA + dst, pA0 + ko); stage16(nb + OA + 8192 + dst, pA1 + ko); }
        PRIO(1);
#pragma unroll
        for (int mf = 0; mf < 4; ++mf)
#pragma unroll
            for (int nf = 0; nf < 2; ++nf)
#pragma unroll
                for (int ks = 0; ks < 2; ++ks)
                    accR[mf][nf] = __builtin_amdgcn_mfma_f32_16x16x32_f16(a[mf][ks], bR[nf][ks], accR[mf][nf], 0, 0, 0);
        PRIO(0);
        if (pf) { VMCNT(4); } else { VMCNT(2); }   // publish L0L1
        BAR();

        // ---- p2: (mi0, L)
#pragma unroll
        for (int nf = 0; nf < 2; ++nf)
#pragma unroll
            for (int ks = 0; ks < 2; ++ks)
                bL[nf][ks] = *(const f16x8*)(base + D_LOFF(nf, ks));
        if (pf) { stage16(nb + OR + dst, pR0 + ko); stage16(nb + OR + 8192 + dst, pR1 + ko); }
        PRIO(1);
#pragma unroll
        for (int mf = 0; mf < 4; ++mf)
#pragma unroll
            for (int nf = 0; nf < 2; ++nf)
#pragma unroll
                for (int ks = 0; ks < 2; ++ks)
                    accL[mf][nf] = __builtin_amdgcn_mfma_f32_16x16x32_f16(a[mf][ks], bL[nf][ks], accL[mf][nf], 0, 0, 0);
        PRIO(0);
        if (pf) { VMCNT(4); } else { VMCNT(0); }   // publish A2A3
        BAR();

        // ---- p3: (mi1, R)
#pragma unroll
        for (int mf = 0; mf < 4; ++mf)
#pragma unroll
            for (int ks = 0; ks < 2; ++ks)
                a[mf][ks] = *(const f16x8*)(base + D_AOFF(1, mf, ks));
        if (pf) { stage16(nb + OL + dst, pL0 + ko); stage16(nb + OL + 8192 + dst, pL1 + ko); }
        PRIO(1);
#pragma unroll
        for (int mf = 0; mf < 4; ++mf)
#pragma unroll
            for (int nf = 0; nf < 2; ++nf)
#pragma unroll
                for (int ks = 0; ks < 2; ++ks)
                    accR[4 + mf][nf] = __builtin_amdgcn_mfma_f32_16x16x32_f16(a[mf][ks], bR[nf][ks], accR[4 + mf][nf], 0, 0, 0);
        PRIO(0);
        BAR();

        // ---- p4: (mi1, L)
        if (pf) { stage16(nb + OA + 16384 + dst, pA2 + ko); stage16(nb + OA + 24576 + dst, pA3 + ko); }
        PRIO(1);
#pragma unroll
        for (int mf = 0; mf < 4; ++mf)
#pragma unroll
            for (int nf = 0; nf < 2; ++nf)
#pragma unroll
                for (int ks = 0; ks < 2; ++ks)
                    accL[4 + mf][nf] = __builtin_amdgcn_mfma_f32_16x16x32_f16(a[mf][ks], bL[nf][ks], accL[4 + mf][nf], 0, 0, 0);
        PRIO(0);
        if (pf) { VMCNT(4); }                      // publish next A0A1,R0R1
        BAR();

        ko += 128;
    }

    // epilogue: bias + bilinear product, fp16 out
#pragma unroll
    for (int nf = 0; nf < 2; ++nf) {
        const int gc = n0 + wn * 32 + nf * 16 + fr;
        const float brv = br[gc], blv = bl[gc];
#pragma unroll
        for (int mi = 0; mi < 2; ++mi)
#pragma unroll
            for (int mf = 0; mf < 4; ++mf) {
                const int gr0 = m0 + wm * 128 + mi * 64 + mf * 16 + fq * 4;
#pragma unroll
                for (int j = 0; j < 4; ++j) {
                    const float rv = accR[mi * 4 + mf][nf][j] + brv;
                    const float lv = accL[mi * 4 + mf][nf][j] + blv;
                    inter[(size_t)(gr0 + j) * HR + gc] = (f16)(rv * lv);
                }
            }
    }
#undef D_AOFF
#undef D_ROFF
#undef D_LOFF
}

// ---------------------------------------------------------------- GEMM2: expand
// Block 256M x 256N, BK=64; 8 waves (2M x 4N); wave 128x64, quadrant walk.
// ONE barrier per phase.  LDS: 2 x (A 32KB + B 32KB) = 128KB.
__global__ __launch_bounds__(512, 2) void k_gemm_expand(
    const f16* __restrict__ Ain, const f16* __restrict__ Wt,
    const float* __restrict__ be, f16* __restrict__ E, int MT)
{
    extern __shared__ __align__(16) char smem[];
    constexpr int NT = 64;                 // 4096 / 64
    constexpr int BUF = 65536;
    constexpr int OA = 0, OB = 32768;

    const int swzb = xcd_swz(blockIdx.x, gridDim.x);
    const int mt = swzb % MT, nt = swzb / MT;
    const int m0 = mt * 256, n0 = nt * 256;
    const int tid = threadIdx.x;
    const int lane = tid & 63, wid = tid >> 6;
    const int wm = wid >> 2, wn = wid & 3;
    const int fr = lane & 15, fq = lane >> 4;
    const int xs = (fr & 7) << 4;
    const int dst = tid * 16;

    const int lr = tid >> 3;
    const int cb = ((tid & 7) << 4) ^ ((lr & 7) << 4);
    const char* pA0 = (const char*)Ain + (size_t)(m0 + lr)       * 8192 + cb;
    const char* pA1 = (const char*)Ain + (size_t)(m0 + 128 + lr) * 8192 + cb;
    const char* pA2 = (const char*)Ain + (size_t)(m0 + 64 + lr)  * 8192 + cb;
    const char* pA3 = (const char*)Ain + (size_t)(m0 + 192 + lr) * 8192 + cb;
    const int r5 = lr & 31, wn2 = lr >> 5;
    const char* pB0 = (const char*)Wt + (size_t)(n0 + wn2 * 64 + r5)        * 8192 + cb;
    const char* pB1 = (const char*)Wt + (size_t)(n0 + (2 + wn2) * 64 + r5)  * 8192 + cb;
    const char* pB2 = (const char*)Wt + (size_t)(n0 + wn2 * 64 + 32 + r5)       * 8192 + cb;
    const char* pB3 = (const char*)Wt + (size_t)(n0 + (2 + wn2) * 64 + 32 + r5) * 8192 + cb;

#define E_AOFF(mi,mf,ks) (OA + ((mi)*128 + wm*64 + (mf)*16 + fr)*128 + ((((ks)*64) + fq*16) ^ xs))
#define E_BOFF(ni,nf,ks) (OB + ((ni)*128 + wn*32 + (nf)*16 + fr)*128 + ((((ks)*64) + fq*16) ^ xs))

    f16x8 a[4][2], b0[2][2], b1[2][2];
    f32x4 acc[8][4] = {};

    stage16(smem + OA + dst, pA0);          stage16(smem + OA + 8192 + dst, pA1);
    stage16(smem + OB + dst, pB0);          stage16(smem + OB + 8192 + dst, pB1);
    stage16(smem + OB + 16384 + dst, pB2);  stage16(smem + OB + 24576 + dst, pB3);
    stage16(smem + OA + 16384 + dst, pA2);  stage16(smem + OA + 24576 + dst, pA3);
    VMCNT(4);
    BAR();

    long ko = 128;
    for (int t = 0; t < NT; ++t) {
        char* base = smem + (t & 1) * BUF;
        char* nb   = smem + ((t & 1) ^ 1) * BUF;
        const bool pf = (t + 1) < NT;

        // ---- p1: (mi0, ni0)
#pragma unroll
        for (int mf = 0; mf < 4; ++mf)
#pragma unroll
            for (int ks = 0; ks < 2; ++ks)
                a[mf][ks] = *(const f16x8*)(base + E_AOFF(0, mf, ks));
#pragma unroll
        for (int nf = 0; nf < 2; ++nf)
#pragma unroll
            for (int ks = 0; ks < 2; ++ks)
                b0[nf][ks] = *(const f16x8*)(base + E_BOFF(0, nf, ks));
        if (pf) { stage16(nb + OA + dst, pA0 + ko); stage16(nb + OA + 8192 + dst, pA1 + ko); }
        PRIO(1);
#pragma unroll
        for (int mf = 0; mf < 4; ++mf)
#pragma unroll
            for (int nf = 0; nf < 2; ++nf)
#pragma unroll
                for (int ks = 0; ks < 2; ++ks)
                    acc[mf][nf] = __builtin_amdgcn_mfma_f32_16x16x32_f16(a[mf][ks], b0[nf][ks], acc[mf][nf], 0, 0, 0);
        PRIO(0);
        if (pf) { VMCNT(4); } else { VMCNT(2); }   // publish B2B3 (ni1)
        BAR();

        // ---- p2: (mi0, ni1)
#pragma unroll
        for (int nf = 0; nf < 2; ++nf)
#pragma unroll
            for (int ks = 0; ks < 2; ++ks)
                b1[nf][ks] = *(const f16x8*)(base + E_BOFF(1, nf, ks));
        if (pf) { stage16(nb + OB + dst, pB0 + ko); stage16(nb + OB + 8192 + dst, pB1 + ko); }
        PRIO(1);
#pragma unroll
        for (int mf = 0; mf < 4; ++mf)
#pragma unroll
            for (int nf = 0; nf < 2; ++nf)
#pragma unroll
                for (int ks = 0; ks < 2; ++ks)
                    acc[mf][2 + nf] = __builtin_amdgcn_mfma_f32_16x16x32_f16(a[mf][ks], b1[nf][ks], acc[mf][2 + nf], 0, 0, 0);
        PRIO(0);
        if (pf) { VMCNT(4); } else { VMCNT(0); }   // publish A2A3
        BAR();

        // ---- p3: (mi1, ni0)
#pragma unroll
        for (int mf = 0; mf < 4; ++mf)
#pragma unroll
            for (int ks = 0; ks < 2; ++ks)
                a[mf][ks] = *(const f16x8*)(base + E_AOFF(1, mf, ks));
        if (pf) { stage16(nb + OB + 16384 + dst, pB2 + ko); stage16(nb + OB + 24576 + dst, pB3 + ko); }
        PRIO(1);
#pragma unroll
        for (int mf = 0; mf < 4; ++mf)
#pragma unroll
            for (int nf = 0; nf < 2; ++nf)
#pragma unroll
                for (int ks = 0; ks < 2; ++ks)
                    acc[4 + mf][nf] = __builtin_amdgcn_mfma_f32_16x16x32_f16(a[mf][ks], b0[nf][ks], acc[4 + mf][nf], 0, 0, 0);
        PRIO(0);
        BAR();

        // ---- p4: (mi1, ni1)
        if (pf) { stage16(nb + OA + 16384 + dst, pA2 + ko); stage16(nb + OA + 24576 + dst, pA3 + ko); }
        PRIO(1);
#pragma unroll
        for (int mf = 0; mf < 4; ++mf)
#pragma unroll
            for (int nf = 0; nf < 2; ++nf)
#pragma unroll
                for (int ks = 0; ks < 2; ++ks)
                    acc[4 + mf][2 + nf] = __builtin_amdgcn_mfma_f32_16x16x32_f16(a[mf][ks], b1[nf][ks], acc[4 + mf][2 + nf], 0, 0, 0);
        PRIO(0);
        if (pf) { VMCNT(4); }                      // publish next A0A1,B0B1
        BAR();

        ko += 128;
    }

#pragma unroll
    for (int ni = 0; ni < 2; ++ni)
#pragma unroll
        for (int nf = 0; nf < 2; ++nf) {
            const int gc = n0 + wn * 64 + ni * 32 + nf * 16 + fr;
            const float bev = be[gc];
#pragma unroll
            for (int mi = 0; mi < 2; ++mi)
#pragma unroll
                for (int mf = 0; mf < 4; ++mf) {
                    const int gr0 = m0 + wm * 128 + mi * 64 + mf * 16 + fq * 4;
#pragma unroll
                    for (int j = 0; j < 4; ++j)
                        E[(size_t)(gr0 + j) * D + gc] = (f16)(acc[mi * 4 + mf][ni * 2 + nf][j] + bev);
                }
        }
#undef E_AOFF
#undef E_BOFF
}

// ---------------------------------------------------------------- residual + LayerNorm
template <typename TR>
__global__ __launch_bounds__(256) void k_ln(
    const TR* __restrict__ X, const f16* __restrict__ Eb,
    const float* __restrict__ g, const float* __restrict__ bb,
    f16* __restrict__ Hh)
{
    const int wid = threadIdx.x >> 6, lane = threadIdx.x & 63;
    const int row = blockIdx.x * 4 + wid;
    const TR* xr = X + (size_t)row * D;
    const f16* er = Eb + (size_t)row * D;
    float v[16];
    float s = 0.f, sq = 0.f;
#pragma unroll
    for (int k = 0; k < 16; ++k) {
        const int c = lane + 64 * k;
        v[k] = (float)xr[c] + (float)er[c];
        s += v[k];
        sq += v[k] * v[k];
    }
#pragma unroll
    for (int off = 32; off; off >>= 1) {
        s += __shfl_down(s, off);
        sq += __shfl_down(sq, off);
    }
    s = __shfl(s, 0);
    sq = __shfl(sq, 0);
    const float mu = s * (1.0f / D);
    const float var = sq * (1.0f / D) - mu * mu;
    const float rs = rsqrtf(var + 1e-5f);
    f16* hh = Hh + (size_t)row * D;
#pragma unroll
    for (int k = 0; k < 16; ++k) {
        const int c = lane + 64 * k;
        const float o = (v[k] - mu) * rs * g[c] + bb[c];
        hh[c] = (f16)o;
    }
}

// ---------------------------------------------------------------- head
__global__ __launch_bounds__(256) void k_head(
    const f16* __restrict__ Hf, const float* __restrict__ Wf,
    const float* __restrict__ bf, float* __restrict__ outp)
{
    __shared__ float wfs[NOUT * D];
    for (int i = threadIdx.x; i < NOUT * D; i += 256) wfs[i] = Wf[i];
    __syncthreads();
    const int wid = threadIdx.x >> 6, lane = threadIdx.x & 63;
    const int row = blockIdx.x * 4 + wid;
    const f16* hr = Hf + (size_t)row * D;
    float hv[16];
#pragma unroll
    for (int k = 0; k < 16; ++k) hv[k] = (float)hr[lane + 64 * k];
#pragma unroll
    for (int j = 0; j < NOUT; ++j) {
        float p = 0.f;
#pragma unroll
        for (int k = 0; k < 16; ++k) p += hv[k] * wfs[j * D + lane + 64 * k];
#pragma unroll
        for (int off = 32; off; off >>= 1) p += __shfl_down(p, off);
        if (lane == 0) outp[(size_t)row * NOUT + j] = p + bf[j];
    }
}

// ---------------------------------------------------------------- launch
extern "C" void kernel_launch(void* const* d_in, const int* in_sizes, int n_in,
                              void* d_out, int out_size, void* d_ws, size_t ws_size,
                              hipStream_t stream) {
    (void)in_sizes; (void)n_in; (void)out_size;
    const float* x   = (const float*)d_in[0];
    const float* wr1 = (const float*)d_in[1];
    const float* br1 = (const float*)d_in[2];
    const float* wl1 = (const float*)d_in[3];
    const float* bl1 = (const float*)d_in[4];
    const float* we1 = (const float*)d_in[5];
    const float* be1 = (const float*)d_in[6];
    const float* g1  = (const float*)d_in[7];
    const float* b1  = (const float*)d_in[8];
    const float* wr2 = (const float*)d_in[9];
    const float* br2 = (const float*)d_in[10];
    const float* wl2 = (const float*)d_in[11];
    const float* bl2 = (const float*)d_in[12];
    const float* we2 = (const float*)d_in[13];
    const float* be2 = (const float*)d_in[14];
    const float* g2  = (const float*)d_in[15];
    const float* b2  = (const float*)d_in[16];
    const float* wf  = (const float*)d_in[17];
    const float* bf  = (const float*)d_in[18];
    float* outp = (float*)d_out;

    constexpr size_t SZ_W16 = (size_t)HR * D * sizeof(f16);
    constexpr size_t SZ_A16 = (size_t)BATCH * D * sizeof(f16);
    constexpr int SMEM = 2 * 65536;

    hipFuncSetAttribute((const void*)k_gemm_dual,   hipFuncAttributeMaxDynamicSharedMemorySize, SMEM);
    hipFuncSetAttribute((const void*)k_gemm_expand, hipFuncAttributeMaxDynamicSharedMemorySize, SMEM);

    char* p = (char*)d_ws;
    f16* wrh = (f16*)p; p += SZ_W16;
    f16* wlh = (f16*)p; p += SZ_W16;
    f16* weh = (f16*)p; p += SZ_W16;
    f16* xh  = (f16*)p; p += SZ_A16;
    f16* h1h = (f16*)p; p += SZ_A16;
    f16* Eh  = (f16*)p; p += SZ_A16;
    f16* interh = (f16*)p;
    const size_t base = (size_t)(p - (char*)d_ws);
    const size_t avail = ws_size > base ? ws_size - base : 0;

    int CH = 2048;
    if ((size_t)16384 * HR * sizeof(f16) <= avail) CH = 16384;
    else if ((size_t)8192 * HR * sizeof(f16) <= avail) CH = 8192;
    else if ((size_t)4096 * HR * sizeof(f16) <= avail) CH = 4096;

    f16* h2h = xh;
    const int nch = BATCH / CH;
    const int MT = CH / 256;
    const int gDual = MT * (HR / 128);
    const int gExp  = MT * (D / 256);

    constexpr int NW4 = HR * D / 4;
    // block-1 converts: x + 3 weights in one launch
    k_conv4<<<2048, 256, 0, stream>>>(x, xh, BATCH * D / 4,
                                      wr1, wrh, NW4, wl1, wlh, NW4, we1, weh, NW4);

    for (int c = 0; c < nch; ++c) {
        k_gemm_dual<<<gDual, 512, SMEM, stream>>>(xh + (size_t)c * CH * D, wrh, wlh, br1, bl1, interh, MT);
        k_gemm_expand<<<gExp, 512, SMEM, stream>>>(interh, weh, be1, Eh + (size_t)c * CH * D, MT);
    }
    k_ln<float><<<BATCH / 4, 256, 0, stream>>>(x, Eh, g1, b1, h1h);

    // block-2 weight converts (rotate into same bufs; stream order makes this safe)
    k_conv4<<<1536, 256, 0, stream>>>(wr2, wrh, NW4, wl2, wlh, NW4, we2, weh, NW4,
                                      nullptr, nullptr, 0);

    for (int c = 0; c < nch; ++c) {
        k_gemm_dual<<<gDual, 512, SMEM, stream>>>(h1h + (size_t)c * CH * D, wrh, wlh, br2, bl2, interh, MT);
        k_gemm_expand<<<gExp, 512, SMEM, stream>>>(interh, weh, be2, Eh + (size_t)c * CH * D, MT);
    }
    k_ln<f16><<<BATCH / 4, 256, 0, stream>>>(h1h, Eh, g2, b2, h2h);

    k_head<<<BATCH / 4, 256, 0, stream>>>(h2h, wf, bf, outp);
}

// Round 8
// 803.563 us; speedup vs baseline: 1.2875x; 1.0663x over previous
//
#include <hip/hip_runtime.h>
#include <hip/hip_fp16.h>

#define DEV static __device__ __forceinline__

typedef _Float16 f16;
typedef _Float16 f16x8 __attribute__((ext_vector_type(8)));
typedef _Float16 f16x4 __attribute__((ext_vector_type(4)));
typedef float f32x4 __attribute__((ext_vector_type(4)));

constexpr int BATCH = 16384;
constexpr int D = 1024;
constexpr int HR = 4096;
constexpr int NOUT = 10;

// ---------------------------------------------------------------- fused converts (4 segments, any may be empty)
__global__ void k_conv4(const float* __restrict__ s0, f16* __restrict__ d0, int n0,
                        const float* __restrict__ s1, f16* __restrict__ d1, int n1,
                        const float* __restrict__ s2, f16* __restrict__ d2, int n2,
                        const float* __restrict__ s3, f16* __restrict__ d3, int n3) {
    int i = blockIdx.x * blockDim.x + threadIdx.x;
    const int st = gridDim.x * blockDim.x;
    const int tot = n0 + n1 + n2 + n3;
    for (; i < tot; i += st) {
        const float* s; f16* d; int j = i;
        if (j < n0) { s = s0; d = d0; }
        else {
            j -= n0;
            if (j < n1) { s = s1; d = d1; }
            else {
                j -= n1;
                if (j < n2) { s = s2; d = d2; }
                else { j -= n2; s = s3; d = d3; }
            }
        }
        float4 v = reinterpret_cast<const float4*>(s)[j];
        f16x4 h;
        h[0] = (f16)v.x; h[1] = (f16)v.y; h[2] = (f16)v.z; h[3] = (f16)v.w;
        reinterpret_cast<f16x4*>(d)[j] = h;
    }
}

// ---------------------------------------------------------------- helpers
DEV void stage16(void* lds, const void* g) {
    __builtin_amdgcn_global_load_lds(
        (const __attribute__((address_space(1))) void*)g,
        (__attribute__((address_space(3))) void*)lds,
        16, 0, 0);
}

// mt-major-per-XCD block mapping: XCD x owns mt in [x*MT/8, (x+1)*MT/8),
// sweeping that mt-range inner, nt outer.  Requires MT % 8 == 0; bijective.
// Keeps each XCD's A-panel (<=4MB) resident in its private L2.
DEV void xcd_map(int bid, int MT, int& mt, int& nt) {
    const int x = bid & 7, q = bid >> 3;
    const int mpx = MT >> 3;
    nt = q / mpx;
    mt = x * mpx + (q % mpx);
}

#define VMCNT(n) asm volatile("s_waitcnt vmcnt(" #n ")" ::: "memory")
#define BAR()    __builtin_amdgcn_s_barrier()
#define PRIO(p)  __builtin_amdgcn_s_setprio(p)

// ---------------------------------------------------------------- GEMM1: dual projection + bilinear fuse
// Block 256M x 128N-dual, BK=64; 8 waves (2M x 4N); wave 128M x 32N for R AND L.
// 4 phases/K-tile (quadrant walk); ONE barrier per phase, counted vmcnt(4).
// LDS: 2 bufs x (A 32KB + R 16KB + L 16KB) = 128KB.
__global__ __launch_bounds__(512, 2) void k_gemm_dual(
    const f16* __restrict__ Xh, const f16* __restrict__ Wr, const f16* __restrict__ Wl,
    const float* __restrict__ br, const float* __restrict__ bl,
    f16* __restrict__ inter, int MT)
{
    extern __shared__ __align__(16) char smem[];
    constexpr int NT = 16;                 // 1024 / 64
    constexpr int BUF = 65536;
    constexpr int OA = 0, OR = 32768, OL = 49152;

    int mt, nt;
    xcd_map(blockIdx.x, MT, mt, nt);
    const int m0 = mt * 256, n0 = nt * 128;
    const int tid = threadIdx.x;
    const int lane = tid & 63, wid = tid >> 6;
    const int wm = wid >> 2, wn = wid & 3;
    const int fr = lane & 15, fq = lane >> 4;
    const int xs = (fr & 7) << 4;
    const int dst = tid * 16;

    const int lr = tid >> 3;
    const int cb = ((tid & 7) << 4) ^ ((lr & 7) << 4);
    const char* pA0 = (const char*)Xh + (size_t)(m0 + lr)       * 2048 + cb;  // mi0,wm0
    const char* pA1 = (const char*)Xh + (size_t)(m0 + 128 + lr) * 2048 + cb;  // mi0,wm1
    const char* pA2 = (const char*)Xh + (size_t)(m0 + 64 + lr)  * 2048 + cb;  // mi1,wm0
    const char* pA3 = (const char*)Xh + (size_t)(m0 + 192 + lr) * 2048 + cb;  // mi1,wm1
    const char* pR0 = (const char*)Wr + (size_t)(n0 + lr)       * 2048 + cb;
    const char* pR1 = (const char*)Wr + (size_t)(n0 + 64 + lr)  * 2048 + cb;
    const char* pL0 = (const char*)Wl + (size_t)(n0 + lr)       * 2048 + cb;
    const char* pL1 = (const char*)Wl + (size_t)(n0 + 64 + lr)  * 2048 + cb;

#define D_AOFF(mi,mf,ks) (OA + ((mi)*128 + wm*64 + (mf)*16 + fr)*128 + ((((ks)*64) + fq*16) ^ xs))
#define D_ROFF(nf,ks)    (OR + (wn*32 + (nf)*16 + fr)*128 + ((((ks)*64) + fq*16) ^ xs))
#define D_LOFF(nf,ks)    (OL + (wn*32 + (nf)*16 + fr)*128 + ((((ks)*64) + fq*16) ^ xs))

    f16x8 a[4][2], bR[2][2], bL[2][2];
    f32x4 accR[8][2] = {};
    f32x4 accL[8][2] = {};

    // prologue: stage tile 0 in need-order
    stage16(smem + OA + dst, pA0);          stage16(smem + OA + 8192 + dst, pA1);
    stage16(smem + OR + dst, pR0);          stage16(smem + OR + 8192 + dst, pR1);
    stage16(smem + OL + dst, pL0);          stage16(smem + OL + 8192 + dst, pL1);
    stage16(smem + OA + 16384 + dst, pA2);  stage16(smem + OA + 24576 + dst, pA3);
    VMCNT(4);
    BAR();

    long ko = 128;
    for (int t = 0; t < NT; ++t) {
        char* base = smem + (t & 1) * BUF;
        char* nb   = smem + ((t & 1) ^ 1) * BUF;
        const bool pf = (t + 1) < NT;

        // ---- p1: (mi0, R)
#pragma unroll
        for (int mf = 0; mf < 4; ++mf)
#pragma unroll
            for (int ks = 0; ks < 2; ++ks)
                a[mf][ks] = *(const f16x8*)(base + D_AOFF(0, mf, ks));
#pragma unroll
        for (int nf = 0; nf < 2; ++nf)
#pragma unroll
            for (int ks = 0; ks < 2; ++ks)
                bR[nf][ks] = *(const f16x8*)(base + D_ROFF(nf, ks));
        if (pf) { stage16(nb + OA + dst, pA0 + ko); stage16(nb + OA + 8192 + dst, pA1 + ko); }
        PRIO(1);
#pragma unroll
        for (int mf = 0; mf < 4; ++mf)
#pragma unroll
            for (int nf = 0; nf < 2; ++nf)
#pragma unroll
                for (int ks = 0; ks < 2; ++ks)
                    accR[mf][nf] = __builtin_amdgcn_mfma_f32_16x16x32_f16(a[mf][ks], bR[nf][ks], accR[mf][nf], 0, 0, 0);
        PRIO(0);
        if (pf) { VMCNT(4); } else { VMCNT(2); }   // publish L0L1
        BAR();

        // ---- p2: (mi0, L)
#pragma unroll
        for (int nf = 0; nf < 2; ++nf)
#pragma unroll
            for (int ks = 0; ks < 2; ++ks)
                bL[nf][ks] = *(const f16x8*)(base + D_LOFF(nf, ks));
        if (pf) { stage16(nb + OR + dst, pR0 + ko); stage16(nb + OR + 8192 + dst, pR1 + ko); }
        PRIO(1);
#pragma unroll
        for (int mf = 0; mf < 4; ++mf)
#pragma unroll
            for (int nf = 0; nf < 2; ++nf)
#pragma unroll
                for (int ks = 0; ks < 2; ++ks)
                    accL[mf][nf] = __builtin_amdgcn_mfma_f32_16x16x32_f16(a[mf][ks], bL[nf][ks], accL[mf][nf], 0, 0, 0);
        PRIO(0);
        if (pf) { VMCNT(4); } else { VMCNT(0); }   // publish A2A3
        BAR();

        // ---- p3: (mi1, R)
#pragma unroll
        for (int mf = 0; mf < 4; ++mf)
#pragma unroll
            for (int ks = 0; ks < 2; ++ks)
                a[mf][ks] = *(const f16x8*)(base + D_AOFF(1, mf, ks));
        if (pf) { stage16(nb + OL + dst, pL0 + ko); stage16(nb + OL + 8192 + dst, pL1 + ko); }
        PRIO(1);
#pragma unroll
        for (int mf = 0; mf < 4; ++mf)
#pragma unroll
            for (int nf = 0; nf < 2; ++nf)
#pragma unroll
                for (int ks = 0; ks < 2; ++ks)
                    accR[4 + mf][nf] = __builtin_amdgcn_mfma_f32_16x16x32_f16(a[mf][ks], bR[nf][ks], accR[4 + mf][nf], 0, 0, 0);
        PRIO(0);
        BAR();

        // ---- p4: (mi1, L)
        if (pf) { stage16(nb + OA + 16384 + dst, pA2 + ko); stage16(nb + OA + 24576 + dst, pA3 + ko); }
        PRIO(1);
#pragma unroll
        for (int mf = 0; mf < 4; ++mf)
#pragma unroll
            for (int nf = 0; nf < 2; ++nf)
#pragma unroll
                for (int ks = 0; ks < 2; ++ks)
                    accL[4 + mf][nf] = __builtin_amdgcn_mfma_f32_16x16x32_f16(a[mf][ks], bL[nf][ks], accL[4 + mf][nf], 0, 0, 0);
        PRIO(0);
        if (pf) { VMCNT(4); }                      // publish next A0A1,R0R1
        BAR();

        ko += 128;
    }

    // epilogue: bias + bilinear product, fp16 out
#pragma unroll
    for (int nf = 0; nf < 2; ++nf) {
        const int gc = n0 + wn * 32 + nf * 16 + fr;
        const float brv = br[gc], blv = bl[gc];
#pragma unroll
        for (int mi = 0; mi < 2; ++mi)
#pragma unroll
            for (int mf = 0; mf < 4; ++mf) {
                const int gr0 = m0 + wm * 128 + mi * 64 + mf * 16 + fq * 4;
#pragma unroll
                for (int j = 0; j < 4; ++j) {
                    const float rv = accR[mi * 4 + mf][nf][j] + brv;
                    const float lv = accL[mi * 4 + mf][nf][j] + blv;
                    inter[(size_t)(gr0 + j) * HR + gc] = (f16)(rv * lv);
                }
            }
    }
#undef D_AOFF
#undef D_ROFF
#undef D_LOFF
}

// ---------------------------------------------------------------- GEMM2: expand + fused residual
// Block 256M x 256N, BK=64; 8 waves (2M x 4N); wave 128x64, quadrant walk.
// Epilogue writes E = Ain.Wt^T + be + resid (residual fused; resid f32 blk1 / f16 blk2).
__global__ __launch_bounds__(512, 2) void k_gemm_expand_f32r(
    const f16* __restrict__ Ain, const f16* __restrict__ Wt,
    const float* __restrict__ be, const float* __restrict__ resid,
    f16* __restrict__ E, int MT);
__global__ __launch_bounds__(512, 2) void k_gemm_expand_f16r(
    const f16* __restrict__ Ain, const f16* __restrict__ Wt,
    const float* __restrict__ be, const f16* __restrict__ resid,
    f16* __restrict__ E, int MT);

template <typename TR>
DEV void expand_body(const f16* Ain, const f16* Wt, const float* be,
                     const TR* resid, f16* E, int MT)
{
    extern __shared__ __align__(16) char smem[];
    constexpr int NT = 64;                 // 4096 / 64
    constexpr int BUF = 65536;
    constexpr int OA = 0, OB = 32768;

    int mt, nt;
    xcd_map(blockIdx.x, MT, mt, nt);
    const int m0 = mt * 256, n0 = nt * 256;
    const int tid = threadIdx.x;
    const int lane = tid & 63, wid = tid >> 6;
    const int wm = wid >> 2, wn = wid & 3;
    const int fr = lane & 15, fq = lane >> 4;
    const int xs = (fr & 7) << 4;
    const int dst = tid * 16;

    const int lr = tid >> 3;
    const int cb = ((tid & 7) << 4) ^ ((lr & 7) << 4);
    const char* pA0 = (const char*)Ain + (size_t)(m0 + lr)       * 8192 + cb;
    const char* pA1 = (const char*)Ain + (size_t)(m0 + 128 + lr) * 8192 + cb;
    const char* pA2 = (const char*)Ain + (size_t)(m0 + 64 + lr)  * 8192 + cb;
    const char* pA3 = (const char*)Ain + (size_t)(m0 + 192 + lr) * 8192 + cb;
    const int r5 = lr & 31, wn2 = lr >> 5;
    const char* pB0 = (const char*)Wt + (size_t)(n0 + wn2 * 64 + r5)        * 8192 + cb;
    const char* pB1 = (const char*)Wt + (size_t)(n0 + (2 + wn2) * 64 + r5)  * 8192 + cb;
    const char* pB2 = (const char*)Wt + (size_t)(n0 + wn2 * 64 + 32 + r5)       * 8192 + cb;
    const char* pB3 = (const char*)Wt + (size_t)(n0 + (2 + wn2) * 64 + 32 + r5) * 8192 + cb;

#define E_AOFF(mi,mf,ks) (OA + ((mi)*128 + wm*64 + (mf)*16 + fr)*128 + ((((ks)*64) + fq*16) ^ xs))
#define E_BOFF(ni,nf,ks) (OB + ((ni)*128 + wn*32 + (nf)*16 + fr)*128 + ((((ks)*64) + fq*16) ^ xs))

    f16x8 a[4][2], b0[2][2], b1[2][2];
    f32x4 acc[8][4] = {};

    stage16(smem + OA + dst, pA0);          stage16(smem + OA + 8192 + dst, pA1);
    stage16(smem + OB + dst, pB0);          stage16(smem + OB + 8192 + dst, pB1);
    stage16(smem + OB + 16384 + dst, pB2);  stage16(smem + OB + 24576 + dst, pB3);
    stage16(smem + OA + 16384 + dst, pA2);  stage16(smem + OA + 24576 + dst, pA3);
    VMCNT(4);
    BAR();

    long ko = 128;
    for (int t = 0; t < NT; ++t) {
        char* base = smem + (t & 1) * BUF;
        char* nb   = smem + ((t & 1) ^ 1) * BUF;
        const bool pf = (t + 1) < NT;

        // ---- p1: (mi0, ni0)
#pragma unroll
        for (int mf = 0; mf < 4; ++mf)
#pragma unroll
            for (int ks = 0; ks < 2; ++ks)
                a[mf][ks] = *(const f16x8*)(base + E_AOFF(0, mf, ks));
#pragma unroll
        for (int nf = 0; nf < 2; ++nf)
#pragma unroll
            for (int ks = 0; ks < 2; ++ks)
                b0[nf][ks] = *(const f16x8*)(base + E_BOFF(0, nf, ks));
        if (pf) { stage16(nb + OA + dst, pA0 + ko); stage16(nb + OA + 8192 + dst, pA1 + ko); }
        PRIO(1);
#pragma unroll
        for (int mf = 0; mf < 4; ++mf)
#pragma unroll
            for (int nf = 0; nf < 2; ++nf)
#pragma unroll
                for (int ks = 0; ks < 2; ++ks)
                    acc[mf][nf] = __builtin_amdgcn_mfma_f32_16x16x32_f16(a[mf][ks], b0[nf][ks], acc[mf][nf], 0, 0, 0);
        PRIO(0);
        if (pf) { VMCNT(4); } else { VMCNT(2); }   // publish B2B3 (ni1)
        BAR();

        // ---- p2: (mi0, ni1)
#pragma unroll
        for (int nf = 0; nf < 2; ++nf)
#pragma unroll
            for (int ks = 0; ks < 2; ++ks)
                b1[nf][ks] = *(const f16x8*)(base + E_BOFF(1, nf, ks));
        if (pf) { stage16(nb + OB + dst, pB0 + ko); stage16(nb + OB + 8192 + dst, pB1 + ko); }
        PRIO(1);
#pragma unroll
        for (int mf = 0; mf < 4; ++mf)
#pragma unroll
            for (int nf = 0; nf < 2; ++nf)
#pragma unroll
                for (int ks = 0; ks < 2; ++ks)
                    acc[mf][2 + nf] = __builtin_amdgcn_mfma_f32_16x16x32_f16(a[mf][ks], b1[nf][ks], acc[mf][2 + nf], 0, 0, 0);
        PRIO(0);
        if (pf) { VMCNT(4); } else { VMCNT(0); }   // publish A2A3
        BAR();

        // ---- p3: (mi1, ni0)
#pragma unroll
        for (int mf = 0; mf < 4; ++mf)
#pragma unroll
            for (int ks = 0; ks < 2; ++ks)
                a[mf][ks] = *(const f16x8*)(base + E_AOFF(1, mf, ks));
        if (pf) { stage16(nb + OB + 16384 + dst, pB2 + ko); stage16(nb + OB + 24576 + dst, pB3 + ko); }
        PRIO(1);
#pragma unroll
        for (int mf = 0; mf < 4; ++mf)
#pragma unroll
            for (int nf = 0; nf < 2; ++nf)
#pragma unroll
                for (int ks = 0; ks < 2; ++ks)
                    acc[4 + mf][nf] = __builtin_amdgcn_mfma_f32_16x16x32_f16(a[mf][ks], b0[nf][ks], acc[4 + mf][nf], 0, 0, 0);
        PRIO(0);
        BAR();

        // ---- p4: (mi1, ni1)
        if (pf) { stage16(nb + OA + 16384 + dst, pA2 + ko); stage16(nb + OA + 24576 + dst, pA3 + ko); }
        PRIO(1);
#pragma unroll
        for (int mf = 0; mf < 4; ++mf)
#pragma unroll
            for (int nf = 0; nf < 2; ++nf)
#pragma unroll
                for (int ks = 0; ks < 2; ++ks)
                    acc[4 + mf][2 + nf] = __builtin_amdgcn_mfma_f32_16x16x32_f16(a[mf][ks], b1[nf][ks], acc[4 + mf][2 + nf], 0, 0, 0);
        PRIO(0);
        if (pf) { VMCNT(4); }                      // publish next A0A1,B0B1
        BAR();

        ko += 128;
    }

    // epilogue: bias + fused residual, fp16 out
#pragma unroll
    for (int ni = 0; ni < 2; ++ni)
#pragma unroll
        for (int nf = 0; nf < 2; ++nf) {
            const int gc = n0 + wn * 64 + ni * 32 + nf * 16 + fr;
            const float bev = be[gc];
#pragma unroll
            for (int mi = 0; mi < 2; ++mi)
#pragma unroll
                for (int mf = 0; mf < 4; ++mf) {
                    const int gr0 = m0 + wm * 128 + mi * 64 + mf * 16 + fq * 4;
#pragma unroll
                    for (int j = 0; j < 4; ++j) {
                        const float rv = (float)resid[(size_t)(gr0 + j) * D + gc];
                        E[(size_t)(gr0 + j) * D + gc] = (f16)(acc[mi * 4 + mf][ni * 2 + nf][j] + bev + rv);
                    }
                }
        }
#undef E_AOFF
#undef E_BOFF
}

__global__ __launch_bounds__(512, 2) void k_gemm_expand_f32r(
    const f16* __restrict__ Ain, const f16* __restrict__ Wt,
    const float* __restrict__ be, const float* __restrict__ resid,
    f16* __restrict__ E, int MT)
{ expand_body<float>(Ain, Wt, be, resid, E, MT); }

__global__ __launch_bounds__(512, 2) void k_gemm_expand_f16r(
    const f16* __restrict__ Ain, const f16* __restrict__ Wt,
    const float* __restrict__ be, const f16* __restrict__ resid,
    f16* __restrict__ E, int MT)
{ expand_body<f16>(Ain, Wt, be, resid, E, MT); }

// ---------------------------------------------------------------- in-place LayerNorm (residual already fused into EH)
__global__ __launch_bounds__(256) void k_ln(
    f16* __restrict__ EH, const float* __restrict__ g, const float* __restrict__ bb)
{
    const int wid = threadIdx.x >> 6, lane = threadIdx.x & 63;
    const int row = blockIdx.x * 4 + wid;
    f16* er = EH + (size_t)row * D;
    float v[16];
    float s = 0.f, sq = 0.f;
#pragma unroll
    for (int k = 0; k < 16; ++k) {
        const int c = lane + 64 * k;
        v[k] = (float)er[c];
        s += v[k];
        sq += v[k] * v[k];
    }
#pragma unroll
    for (int off = 32; off; off >>= 1) {
        s += __shfl_down(s, off);
        sq += __shfl_down(sq, off);
    }
    s = __shfl(s, 0);
    sq = __shfl(sq, 0);
    const float mu = s * (1.0f / D);
    const float var = sq * (1.0f / D) - mu * mu;
    const float rs = rsqrtf(var + 1e-5f);
#pragma unroll
    for (int k = 0; k < 16; ++k) {
        const int c = lane + 64 * k;
        const float o = (v[k] - mu) * rs * g[c] + bb[c];
        er[c] = (f16)o;
    }
}

// ---------------------------------------------------------------- head
__global__ __launch_bounds__(256) void k_head(
    const f16* __restrict__ Hf, const float* __restrict__ Wf,
    const float* __restrict__ bf, float* __restrict__ outp)
{
    __shared__ float wfs[NOUT * D];
    for (int i = threadIdx.x; i < NOUT * D; i += 256) wfs[i] = Wf[i];
    __syncthreads();
    const int wid = threadIdx.x >> 6, lane = threadIdx.x & 63;
    const int row = blockIdx.x * 4 + wid;
    const f16* hr = Hf + (size_t)row * D;
    float hv[16];
#pragma unroll
    for (int k = 0; k < 16; ++k) hv[k] = (float)hr[lane + 64 * k];
#pragma unroll
    for (int j = 0; j < NOUT; ++j) {
        float p = 0.f;
#pragma unroll
        for (int k = 0; k < 16; ++k) p += hv[k] * wfs[j * D + lane + 64 * k];
#pragma unroll
        for (int off = 32; off; off >>= 1) p += __shfl_down(p, off);
        if (lane == 0) outp[(size_t)row * NOUT + j] = p + bf[j];
    }
}

// ---------------------------------------------------------------- launch
extern "C" void kernel_launch(void* const* d_in, const int* in_sizes, int n_in,
                              void* d_out, int out_size, void* d_ws, size_t ws_size,
                              hipStream_t stream) {
    (void)in_sizes; (void)n_in; (void)out_size;
    const float* x   = (const float*)d_in[0];
    const float* wr1 = (const float*)d_in[1];
    const float* br1 = (const float*)d_in[2];
    const float* wl1 = (const float*)d_in[3];
    const float* bl1 = (const float*)d_in[4];
    const float* we1 = (const float*)d_in[5];
    const float* be1 = (const float*)d_in[6];
    const float* g1  = (const float*)d_in[7];
    const float* b1  = (const float*)d_in[8];
    const float* wr2 = (const float*)d_in[9];
    const float* br2 = (const float*)d_in[10];
    const float* wl2 = (const float*)d_in[11];
    const float* bl2 = (const float*)d_in[12];
    const float* we2 = (const float*)d_in[13];
    const float* be2 = (const float*)d_in[14];
    const float* g2  = (const float*)d_in[15];
    const float* b2  = (const float*)d_in[16];
    const float* wf  = (const float*)d_in[17];
    const float* bf  = (const float*)d_in[18];
    float* outp = (float*)d_out;

    constexpr size_t SZ_W16 = (size_t)HR * D * sizeof(f16);    // 8 MB
    constexpr size_t SZ_A16 = (size_t)BATCH * D * sizeof(f16); // 32 MB
    constexpr int SMEM = 2 * 65536;

    hipFuncSetAttribute((const void*)k_gemm_dual,        hipFuncAttributeMaxDynamicSharedMemorySize, SMEM);
    hipFuncSetAttribute((const void*)k_gemm_expand_f32r, hipFuncAttributeMaxDynamicSharedMemorySize, SMEM);
    hipFuncSetAttribute((const void*)k_gemm_expand_f16r, hipFuncAttributeMaxDynamicSharedMemorySize, SMEM);

    // workspace: weights(24MB) + xh(32MB) + EH(32MB) = 88MB base, rest = inter chunk
    char* p = (char*)d_ws;
    f16* wrh = (f16*)p; p += SZ_W16;
    f16* wlh = (f16*)p; p += SZ_W16;
    f16* weh = (f16*)p; p += SZ_W16;
    f16* xh  = (f16*)p; p += SZ_A16;   // f16 of x (dual-1 input only)
    f16* EH  = (f16*)p; p += SZ_A16;   // E1+x -> h1 (in-place LN) -> E2+h1 -> h2
    f16* interh = (f16*)p;
    const size_t base = (size_t)(p - (char*)d_ws);
    const size_t avail = ws_size > base ? ws_size - base : 0;

    int CH = 2048;
    if ((size_t)16384 * HR * sizeof(f16) <= avail) CH = 16384;
    else if ((size_t)8192 * HR * sizeof(f16) <= avail) CH = 8192;
    else if ((size_t)4096 * HR * sizeof(f16) <= avail) CH = 4096;

    const int nch = BATCH / CH;
    const int MT = CH / 256;
    const int gDual = MT * (HR / 128);
    const int gExp  = MT * (D / 256);

    constexpr int NW4 = HR * D / 4;
    k_conv4<<<2048, 256, 0, stream>>>(x, xh, BATCH * D / 4,
                                      wr1, wrh, NW4, wl1, wlh, NW4, we1, weh, NW4);

    // ---- block 1 (residual x fused into expand epilogue)
    for (int c = 0; c < nch; ++c) {
        k_gemm_dual<<<gDual, 512, SMEM, stream>>>(xh + (size_t)c * CH * D, wrh, wlh, br1, bl1, interh, MT);
        k_gemm_expand_f32r<<<gExp, 512, SMEM, stream>>>(interh, weh, be1, x + (size_t)c * CH * D,
                                                        EH + (size_t)c * CH * D, MT);
    }
    k_ln<<<BATCH / 4, 256, 0, stream>>>(EH, g1, b1);   // EH := h1

    k_conv4<<<1536, 256, 0, stream>>>(wr2, wrh, NW4, wl2, wlh, NW4, we2, weh, NW4,
                                      nullptr, nullptr, 0);

    // ---- block 2 (residual h1 fused; EH overwritten chunk-by-chunk after its dual read)
    for (int c = 0; c < nch; ++c) {
        k_gemm_dual<<<gDual, 512, SMEM, stream>>>(EH + (size_t)c * CH * D, wrh, wlh, br2, bl2, interh, MT);
        k_gemm_expand_f16r<<<gExp, 512, SMEM, stream>>>(interh, weh, be2, EH + (size_t)c * CH * D,
                                                        EH + (size_t)c * CH * D, MT);
    }
    k_ln<<<BATCH / 4, 256, 0, stream>>>(EH, g2, b2);   // EH := h2

    k_head<<<BATCH / 4, 256, 0, stream>>>(EH, wf, bf, outp);
}